// Round 3
// baseline (21849.892 us; speedup 1.0000x reference)
//
#include <hip/hip_runtime.h>
#include <hip/hip_bf16.h>
#include <hip/hip_cooperative_groups.h>
#include <stdint.h>

namespace cg = cooperative_groups;

#define BSZ 512
#define TT  256
#define IIN 64
#define HH  512
#define G4  2048
#define NSTEPS 10

typedef unsigned short ushort_t;
typedef short bf16x8 __attribute__((ext_vector_type(8)));
typedef float f32x4  __attribute__((ext_vector_type(4)));

static constexpr size_t N0W = (size_t)G4 * 576;          // role0 packed weight elems
static constexpr size_t NTW = N0W + (size_t)G4 * 1024;   // + role1

__device__ __forceinline__ ushort_t f2bf(float f){
  union { float f; uint32_t u; } v; v.f = f;
  uint32_t u = v.u;
  return (ushort_t)((u + 0x7fffu + ((u >> 16) & 1u)) >> 16);
}
__device__ __forceinline__ float bf2f(ushort_t h){
  union { uint32_t u; float f; } v; v.u = ((uint32_t)h) << 16;
  return v.f;
}
__device__ __forceinline__ void split2(float f, ushort_t& h, ushort_t& l){
  h = f2bf(f); l = f2bf(f - bf2f(h));
}
__device__ __forceinline__ float sigf(float x){ return 1.0f/(1.0f+__expf(-x)); }
__device__ __forceinline__ float tanhfast(float x){ return 1.0f - 2.0f/(__expf(2.0f*x)+1.0f); }

struct KP {
  const float* x;
  const ushort_t *Wph, *Wpl;
  const float *b0v, *b1v;
  const float *Wlin, *blin;
  ushort_t *h0h0, *h0h1, *h0l0, *h0l1;
  ushort_t *h1h0, *h1h1, *h1l0, *h1l1;
  float *c0, *c1;
  ushort_t *outh, *outl;
  float* out;
};

// ---------------------------------------------------------------------------
// One LSTM cell tile: 64 batch rows (b0..) x (4 gates x 16 h-cols at j0..).
// Waves: w = (mh<<1)|km. km = K-half of each 64k round, mh = 32-row half.
// Per round (64 k = 2 chunks of 32): stage A/B hi+lo into 4x 8KB LDS buffers
// (XOR-swizzled 16B units), each wave does 2m x 4n x 3 = 24 MFMAs (bf16x3).
// End: km=1 waves dump partials (16KB), km=0 waves add + in-register pointwise.
// LDS total: 32 KB.
// ---------------------------------------------------------------------------
__device__ __forceinline__ void cell_tile(ushort_t* lds,
  int b0, int j0,
  const float* a1f, const ushort_t* a1h, const ushort_t* a1l, int a1s, int k1,
  const ushort_t* a2h, const ushort_t* a2l,
  const ushort_t* wpbh, const ushort_t* wpbl, int K, int nrounds,
  const float* bias, float* cbuf, ushort_t* houth, ushort_t* houtl)
{
  const int tid = threadIdx.x;
  const int w  = tid >> 6;
  const int l  = tid & 63;
  const int km = w & 1;
  const int mh = w >> 1;
  const int lr = l & 15;
  const int kh = l >> 4;

  f32x4 acc[2][4];
  #pragma unroll
  for (int mm=0; mm<2; ++mm)
    #pragma unroll
    for (int nn=0; nn<4; ++nn)
      acc[mm][nn] = (f32x4){0.f,0.f,0.f,0.f};

  ushort_t* sAh = lds;
  ushort_t* sAl = lds + 4096;
  ushort_t* sBh = lds + 8192;
  ushort_t* sBl = lds + 12288;

  for (int r = 0; r < nrounds; ++r){
    // ---- stage 64k round: A rows 0..63 (batch), B rows 0..63 (gate-cols) ----
    #pragma unroll
    for (int q = 0; q < 2; ++q){
      int u   = q*256 + tid;
      int row = u >> 3;
      int j   = u & 7;
      int jl  = j ^ (row & 7);
      int klog = r*64 + jl*8;
      int didx = u * 8;
      bf16x8 hv, lv;
      if (klog < k1){
        if (a1f){
          const float* ps = a1f + (size_t)(b0+row)*a1s + klog;
          f32x4 u0 = *(const f32x4*)ps;
          f32x4 u1 = *(const f32x4*)(ps+4);
          union { ushort_t us[8]; bf16x8 v; } H, L;
          #pragma unroll
          for (int jj=0;jj<4;++jj) split2(u0[jj], H.us[jj],   L.us[jj]);
          #pragma unroll
          for (int jj=0;jj<4;++jj) split2(u1[jj], H.us[4+jj], L.us[4+jj]);
          hv = H.v; lv = L.v;
        } else {
          hv = *(const bf16x8*)&a1h[(size_t)(b0+row)*a1s + klog];
          lv = *(const bf16x8*)&a1l[(size_t)(b0+row)*a1s + klog];
        }
      } else {
        int kk = klog - k1;
        hv = *(const bf16x8*)&a2h[(size_t)((b0+row)<<9) + kk];
        lv = *(const bf16x8*)&a2l[(size_t)((b0+row)<<9) + kk];
      }
      *(bf16x8*)&sAh[didx] = hv;
      *(bf16x8*)&sAl[didx] = lv;
      size_t bsrc = (size_t)row*K + klog;
      *(bf16x8*)&sBh[didx] = *(const bf16x8*)&wpbh[bsrc];
      *(bf16x8*)&sBl[didx] = *(const bf16x8*)&wpbl[bsrc];
    }
    __syncthreads();
    // ---- compute: wave takes chunk km (units km*4 .. km*4+3) ----
    const int ju = km*4 + kh;
    bf16x8 ah[2], al[2];
    #pragma unroll
    for (int mm=0; mm<2; ++mm){
      int rowa = (mh*2+mm)*16 + lr;
      int idx = (rowa*8 + (ju ^ (rowa&7)))*8;
      ah[mm] = *(bf16x8*)&sAh[idx];
      al[mm] = *(bf16x8*)&sAl[idx];
    }
    #pragma unroll
    for (int nn=0; nn<4; ++nn){
      int rowb = nn*16 + lr;
      int idx = (rowb*8 + (ju ^ (rowb&7)))*8;
      bf16x8 bh = *(bf16x8*)&sBh[idx];
      bf16x8 bl = *(bf16x8*)&sBl[idx];
      #pragma unroll
      for (int mm=0; mm<2; ++mm){
        acc[mm][nn] = __builtin_amdgcn_mfma_f32_16x16x32_bf16(ah[mm], bh, acc[mm][nn],0,0,0);
        acc[mm][nn] = __builtin_amdgcn_mfma_f32_16x16x32_bf16(ah[mm], bl, acc[mm][nn],0,0,0);
        acc[mm][nn] = __builtin_amdgcn_mfma_f32_16x16x32_bf16(al[mm], bh, acc[mm][nn],0,0,0);
      }
    }
    __syncthreads();
  }

  // ---- cross-wave reduction (km pair) ----
  float* sR = (float*)lds;           // 2 regions x 2048 floats (16 KB)
  if (km == 1){
    #pragma unroll
    for (int mm=0; mm<2; ++mm)
      #pragma unroll
      for (int nn=0; nn<4; ++nn){
        int c = mm*4 + nn;
        *(f32x4*)&sR[mh*2048 + l*32 + (c ^ (l&7))*4] = acc[mm][nn];
      }
  }
  __syncthreads();
  if (km == 0){
    #pragma unroll
    for (int mm=0; mm<2; ++mm)
      #pragma unroll
      for (int nn=0; nn<4; ++nn){
        int c = mm*4 + nn;
        acc[mm][nn] += *(f32x4*)&sR[mh*2048 + l*32 + (c ^ (l&7))*4];
      }
    // ---- in-register pointwise: lane holds all 4 gates for its h-col ----
    float bi = bias[       j0 + lr];
    float bf = bias[ 512 + j0 + lr];
    float bg = bias[1024 + j0 + lr];
    float bo = bias[1536 + j0 + lr];
    #pragma unroll
    for (int mm=0; mm<2; ++mm){
      #pragma unroll
      for (int q=0; q<4; ++q){
        int row = (mh*2+mm)*16 + kh*4 + q;
        float gi = acc[mm][0][q] + bi;
        float gf = acc[mm][1][q] + bf;
        float gg = acc[mm][2][q] + bg;
        float go = acc[mm][3][q] + bo;
        size_t gidx = (size_t)((b0+row)<<9) + j0 + lr;
        float cold = cbuf[gidx];
        float cn = sigf(gf)*cold + sigf(gi)*tanhfast(gg);
        cbuf[gidx] = cn;
        float hval = sigf(go)*tanhfast(cn);
        ushort_t hh2, hl2; split2(hval, hh2, hl2);
        houth[gidx] = hh2; houtl[gidx] = hl2;
      }
    }
  }
  __syncthreads();
}

// ---- phase bodies (shared by persistent kernel and fallback kernels) ----
__device__ __forceinline__ void do_enc(const KP& p, ushort_t* lds, int bid, int s){
  const int role = bid >> 8;
  const int tile = bid & 255;
  const int m = tile >> 5, nt = tile & 31;
  const int b0 = m*64, j0 = nt*16;
  ushort_t* h0h[2] = { p.h0h0, p.h0h1 };
  ushort_t* h0l[2] = { p.h0l0, p.h0l1 };
  ushort_t* h1h[2] = { p.h1h0, p.h1h1 };
  ushort_t* h1l[2] = { p.h1l0, p.h1l1 };
  if (role == 0){
    if (s >= TT) return;
    const int t = s;
    cell_tile(lds, b0, j0,
      p.x + (size_t)t*IIN, nullptr, nullptr, TT*IIN, 64,
      h0h[(t+1)&1], h0l[(t+1)&1],
      p.Wph + (size_t)nt*64*576, p.Wpl + (size_t)nt*64*576, 576, 9,
      p.b0v, p.c0, h0h[t&1], h0l[t&1]);
  } else {
    if (s < 1) return;
    const int t = s-1;
    cell_tile(lds, b0, j0,
      nullptr, h0h[t&1], h0l[t&1], 512, 512,
      h1h[(t+1)&1], h1l[(t+1)&1],
      p.Wph + N0W + (size_t)nt*64*1024, p.Wpl + N0W + (size_t)nt*64*1024, 1024, 16,
      p.b1v, p.c1, h1h[t&1], h1l[t&1]);
  }
}

__device__ __forceinline__ void do_dec0(const KP& p, ushort_t* lds, int tile, int d, int p0){
  const int m = tile >> 5, nt = tile & 31;
  const int b0 = m*64, j0 = nt*16;
  ushort_t* h0h[2] = { p.h0h0, p.h0h1 };
  ushort_t* h0l[2] = { p.h0l0, p.h0l1 };
  const ushort_t* w0h = p.Wph + (size_t)nt*64*576;
  const ushort_t* w0l = p.Wpl + (size_t)nt*64*576;
  if (d == 0)
    cell_tile(lds, b0, j0,
      p.x + (size_t)(TT-1)*IIN, nullptr, nullptr, TT*IIN, 64,
      h0h[p0], h0l[p0], w0h, w0l, 576, 9,
      p.b0v, p.c0, h0h[1-p0], h0l[1-p0]);
  else
    cell_tile(lds, b0, j0,
      nullptr, p.outh, p.outl, 64, 64,
      h0h[p0], h0l[p0], w0h, w0l, 576, 9,
      p.b0v, p.c0, h0h[1-p0], h0l[1-p0]);
}

__device__ __forceinline__ void do_dec1(const KP& p, ushort_t* lds, int tile, int p0, int p1){
  const int m = tile >> 5, nt = tile & 31;
  const int b0 = m*64, j0 = nt*16;
  ushort_t* h0h[2] = { p.h0h0, p.h0h1 };
  ushort_t* h0l[2] = { p.h0l0, p.h0l1 };
  ushort_t* h1h[2] = { p.h1h0, p.h1h1 };
  ushort_t* h1l[2] = { p.h1l0, p.h1l1 };
  cell_tile(lds, b0, j0,
    nullptr, h0h[1-p0], h0l[1-p0], 512, 512,
    h1h[p1], h1l[p1],
    p.Wph + N0W + (size_t)nt*64*1024, p.Wpl + N0W + (size_t)nt*64*1024, 1024, 16,
    p.b1v, p.c1, h1h[1-p1], h1l[1-p1]);
}

__device__ __forceinline__ void do_lin(const KP& p, int bid, int d, int p1){
  ushort_t* h1h[2] = { p.h1h0, p.h1h1 };
  ushort_t* h1l[2] = { p.h1l0, p.h1l1 };
  const ushort_t* hhp = h1h[1-p1];
  const ushort_t* hlp = h1l[1-p1];
  int row = bid*4 + (threadIdx.x >> 6);
  int i   = threadIdx.x & 63;
  const float* wr = p.Wlin + (size_t)i*512;
  float ssum = 0.f;
  for (int k = 0; k < 512; k += 8){
    bf16x8 vh = *(const bf16x8*)&hhp[(size_t)(row<<9)+k];
    bf16x8 vl = *(const bf16x8*)&hlp[(size_t)(row<<9)+k];
    #pragma unroll
    for (int jj=0;jj<8;++jj)
      ssum += (bf2f((ushort_t)vh[jj]) + bf2f((ushort_t)vl[jj])) * wr[k+jj];
  }
  ssum += p.blin[i];
  p.out[(size_t)row*(NSTEPS*IIN) + d*IIN + i] = ssum;
  ushort_t oh, ol; split2(ssum, oh, ol);
  p.outh[row*64 + i] = oh;
  p.outl[row*64 + i] = ol;
}

// ---- persistent cooperative kernel ----
__global__ __launch_bounds__(256, 2)
void lstm_persist(KP p)
{
  const int bid = blockIdx.x;
  __shared__ ushort_t lds[16384];   // 32 KB
  cg::grid_group grid = cg::this_grid();

  for (int s = 0; s <= TT; ++s){
    do_enc(p, lds, bid, s);
    grid.sync();
  }
  int p0 = 1, p1 = 1;
  for (int d = 0; d < NSTEPS; ++d){
    if (bid < 256) do_dec0(p, lds, bid, d, p0);
    grid.sync();
    if (bid >= 256) do_dec1(p, lds, bid & 255, p0, p1);
    grid.sync();
    if (bid < 128) do_lin(p, bid, d, p1);
    grid.sync();
    p0 ^= 1; p1 ^= 1;
  }
}

// ---- fallback per-step kernels (same device code, separate launches) ----
__global__ __launch_bounds__(256, 2)
void fb_enc(KP p, int s){
  __shared__ ushort_t lds[16384];
  do_enc(p, lds, blockIdx.x, s);
}
__global__ __launch_bounds__(256, 2)
void fb_dec0(KP p, int d, int p0){
  __shared__ ushort_t lds[16384];
  do_dec0(p, lds, blockIdx.x, d, p0);
}
__global__ __launch_bounds__(256, 2)
void fb_dec1(KP p, int p0, int p1){
  __shared__ ushort_t lds[16384];
  do_dec1(p, lds, blockIdx.x, p0, p1);
}
__global__ __launch_bounds__(256)
void fb_lin(KP p, int d, int p1){
  do_lin(p, blockIdx.x, d, p1);
}

// ---- prep kernels ----
__global__ void bias_kernel(const float* a, const float* b, float* o){
  int i = blockIdx.x * 256 + threadIdx.x;
  if (i < G4) o[i] = a[i] + b[i];
}

__global__ void prep_w(const float* __restrict__ Wih0, const float* __restrict__ Whh0,
                       const float* __restrict__ Wih1, const float* __restrict__ Whh1,
                       ushort_t* __restrict__ Wph, ushort_t* __restrict__ Wpl)
{
  size_t i = (size_t)blockIdx.x*256 + threadIdx.x;
  if (i >= NTW) return;
  float val;
  if (i < N0W){
    size_t e = i;
    int nt = (int)(e / (64*576)); int rem = (int)(e % (64*576));
    int cl = rem / 576; int k = rem % 576;
    int grow = (cl>>4)*512 + nt*16 + (cl&15);
    val = (k < 64) ? Wih0[(size_t)grow*64 + k] : Whh0[(size_t)grow*512 + (k-64)];
  } else {
    size_t e = i - N0W;
    int nt = (int)(e >> 16); int rem = (int)(e & 65535);   // 64*1024
    int cl = rem >> 10; int k = rem & 1023;
    int grow = (cl>>4)*512 + nt*16 + (cl&15);
    val = (k < 512) ? Wih1[(size_t)grow*512 + k] : Whh1[(size_t)grow*512 + (k-512)];
  }
  ushort_t h, lo2; split2(val, h, lo2);
  Wph[i] = h; Wpl[i] = lo2;
}

extern "C" void kernel_launch(void* const* d_in, const int* in_sizes, int n_in,
                              void* d_out, int out_size, void* d_ws, size_t ws_size,
                              hipStream_t stream)
{
  const float* x     = (const float*)d_in[0];
  const float* W_ih0 = (const float*)d_in[1];
  const float* W_hh0 = (const float*)d_in[2];
  const float* b_ih0 = (const float*)d_in[3];
  const float* b_hh0 = (const float*)d_in[4];
  const float* W_ih1 = (const float*)d_in[5];
  const float* W_hh1 = (const float*)d_in[6];
  const float* b_ih1 = (const float*)d_in[7];
  const float* b_hh1 = (const float*)d_in[8];
  const float* W_lin = (const float*)d_in[9];
  const float* b_lin = (const float*)d_in[10];

  char* ws = (char*)d_ws;
  size_t off = 0;
  auto alloc = [&](size_t bytes){ size_t o = off; off += (bytes + 255) & ~(size_t)255; return o; };

  float* b0v = (float*)(ws + alloc(G4*4));
  float* b1v = (float*)(ws + alloc(G4*4));
  ushort_t* Wph = (ushort_t*)(ws + alloc(NTW*2));
  ushort_t* Wpl = (ushort_t*)(ws + alloc(NTW*2));

  const size_t BH = (size_t)BSZ * HH;      // 262144
  size_t statesBytes = 8*BH*2 + 2*BH*4 + 2*(size_t)BSZ*IIN*2;
  char* states = ws + alloc(statesBytes);
  ushort_t* hbufs = (ushort_t*)states;
  ushort_t* h0h0 = hbufs;          ushort_t* h0h1 = hbufs + BH;
  ushort_t* h0l0 = hbufs + 2*BH;   ushort_t* h0l1 = hbufs + 3*BH;
  ushort_t* h1h0 = hbufs + 4*BH;   ushort_t* h1h1 = hbufs + 5*BH;
  ushort_t* h1l0 = hbufs + 6*BH;   ushort_t* h1l1 = hbufs + 7*BH;
  float* c0 = (float*)(states + 8*BH*2);
  float* c1 = c0 + BH;
  ushort_t* outh = (ushort_t*)(states + 8*BH*2 + 2*BH*4);
  ushort_t* outl = outh + (size_t)BSZ*IIN;

  // ---- prep ----
  bias_kernel<<<(G4+255)/256, 256, 0, stream>>>(b_ih0, b_hh0, b0v);
  bias_kernel<<<(G4+255)/256, 256, 0, stream>>>(b_ih1, b_hh1, b1v);
  prep_w<<<(int)((NTW+255)/256), 256, 0, stream>>>(W_ih0, W_hh0, W_ih1, W_hh1, Wph, Wpl);
  hipMemsetAsync(states, 0, statesBytes, stream);

  KP kp;
  kp.x = x; kp.Wph = Wph; kp.Wpl = Wpl; kp.b0v = b0v; kp.b1v = b1v;
  kp.Wlin = W_lin; kp.blin = b_lin;
  kp.h0h0 = h0h0; kp.h0h1 = h0h1; kp.h0l0 = h0l0; kp.h0l1 = h0l1;
  kp.h1h0 = h1h0; kp.h1h1 = h1h1; kp.h1l0 = h1l0; kp.h1l1 = h1l1;
  kp.c0 = c0; kp.c1 = c1; kp.outh = outh; kp.outl = outl;
  kp.out = (float*)d_out;

  // ---- try persistent cooperative kernel; fall back to per-step launches ----
  void* kargs[] = { &kp };
  hipError_t ce = hipLaunchCooperativeKernel((void*)lstm_persist,
                                             dim3(512), dim3(256), kargs, 0, stream);
  if (ce != hipSuccess){
    for (int s = 0; s <= TT; ++s)
      fb_enc<<<512, 256, 0, stream>>>(kp, s);
    int p0 = 1, p1 = 1;
    for (int d = 0; d < NSTEPS; ++d){
      fb_dec0<<<256, 256, 0, stream>>>(kp, d, p0);
      fb_dec1<<<256, 256, 0, stream>>>(kp, p0, p1);
      fb_lin<<<128, 256, 0, stream>>>(kp, d, p1);
      p0 ^= 1; p1 ^= 1;
    }
  }
}

// Round 4
// 15117.006 us; speedup vs baseline: 1.4454x; 1.4454x over previous
//
#include <hip/hip_runtime.h>
#include <hip/hip_bf16.h>
#include <stdint.h>

#define BSZ 512
#define TT  256
#define IIN 64
#define HH  512
#define G4  2048
#define NSTEPS 10
#define NBLOCKS 512

typedef unsigned short ushort_t;
typedef short bf16x8 __attribute__((ext_vector_type(8)));
typedef float f32x4  __attribute__((ext_vector_type(4)));

static constexpr size_t N0W = (size_t)G4 * 576;          // role0 packed weight elems
static constexpr size_t NTW = N0W + (size_t)G4 * 1024;   // + role1

__device__ __forceinline__ ushort_t f2bf(float f){
  union { float f; uint32_t u; } v; v.f = f;
  uint32_t u = v.u;
  return (ushort_t)((u + 0x7fffu + ((u >> 16) & 1u)) >> 16);
}
__device__ __forceinline__ float bf2f(ushort_t h){
  union { uint32_t u; float f; } v; v.u = ((uint32_t)h) << 16;
  return v.f;
}
__device__ __forceinline__ void split2(float f, ushort_t& h, ushort_t& l){
  h = f2bf(f); l = f2bf(f - bf2f(h));
}
__device__ __forceinline__ float sigf(float x){ return 1.0f/(1.0f+__expf(-x)); }
__device__ __forceinline__ float tanhfast(float x){ return 1.0f - 2.0f/(__expf(2.0f*x)+1.0f); }

// device-coherent (agent-scope) data movement: bypasses stale L1/L2, no fences
__device__ __forceinline__ unsigned long long aload_u64(const uint32_t* p){
  return __hip_atomic_load((const unsigned long long*)p, __ATOMIC_RELAXED,
                           __HIP_MEMORY_SCOPE_AGENT);
}
__device__ __forceinline__ void astore_u32(uint32_t* p, uint32_t v){
  __hip_atomic_store(p, v, __ATOMIC_RELAXED, __HIP_MEMORY_SCOPE_AGENT);
}

struct KP {
  const float* x;
  const uint32_t* Wp;            // packed weights: u32 = hi | (lo<<16)
  const float *b0v, *b1v;
  const float *Wlin, *blin;
  uint32_t *h0p0, *h0p1, *h1p0, *h1p1;   // packed h double buffers
  float *c0, *c1;
  uint32_t *outp;                // packed decoder feedback
  float* out;
  uint32_t* bar;                 // barrier counters
};

// per-thread staging registers for one (q) slice of one round
struct SR {
  unsigned long long a[4];       // 8 packed-u32 A elems (or 8 f32 bit-packed)
  uint4 b0, b1;                  // 8 packed-u32 B elems
};

// ---------------------------------------------------------------------------
// One LSTM cell tile: 64 batch rows (b0..) x (4 gates x 16 h-cols at j0..).
// Waves: w = (mh<<1)|km. Per 64k round: stage A/B hi+lo into 4x 8KB LDS
// buffers (XOR-swizzled 16B units), each wave does 2m x 4n x 3 = 24 MFMAs
// (bf16x3). Register double-buffered staging (prefetch round r+1 during r).
// A rounds < r1 come from a1f (f32) or a1p (packed); rounds >= r1 from a2p
// (packed, stride 512). End: km=1 waves dump partials, km=0 add + pointwise.
// ---------------------------------------------------------------------------
__device__ __forceinline__ void cell_tile(ushort_t* lds,
  int b0, int j0,
  const float* a1f, const uint32_t* a1p, int a1stride, int r1,
  const uint32_t* a2p,
  const uint32_t* wp, int K, int nrounds,
  const float* bias, float* cbuf, uint32_t* houtp)
{
  const int tid = threadIdx.x;
  const int w  = tid >> 6;
  const int l  = tid & 63;
  const int km = w & 1;
  const int mh = w >> 1;
  const int lr = l & 15;
  const int kh = l >> 4;

  const int jrow0 = tid >> 3;            // staging row for q=0 (q=1: +32)
  const int jj    = tid & 7;
  const int jl    = jj ^ (jrow0 & 7);    // (jrow0+32)&7 == jrow0&7
  const int didx0 = (jrow0*8 + jj) * 8;
  const int didx1 = ((jrow0+32)*8 + jj) * 8;

  f32x4 acc[2][4];
  #pragma unroll
  for (int mm=0; mm<2; ++mm)
    #pragma unroll
    for (int nn=0; nn<4; ++nn)
      acc[mm][nn] = (f32x4){0.f,0.f,0.f,0.f};

  ushort_t* sAh = lds;
  ushort_t* sAl = lds + 4096;
  ushort_t* sBh = lds + 8192;
  ushort_t* sBl = lds + 12288;

  auto issue = [&](SR* R, int r){
    const int klog = r*64 + jl*8;
    #pragma unroll
    for (int q=0; q<2; ++q){
      SR& S = R[q];
      const int row = jrow0 + q*32;
      if (r < r1){
        if (a1f){
          const float* ps = a1f + (size_t)(b0+row)*a1stride + klog;
          S.a[0] = *(const unsigned long long*)(ps+0);
          S.a[1] = *(const unsigned long long*)(ps+2);
          S.a[2] = *(const unsigned long long*)(ps+4);
          S.a[3] = *(const unsigned long long*)(ps+6);
        } else {
          const uint32_t* ap = a1p + (size_t)(b0+row)*a1stride + klog;
          S.a[0]=aload_u64(ap);   S.a[1]=aload_u64(ap+2);
          S.a[2]=aload_u64(ap+4); S.a[3]=aload_u64(ap+6);
        }
      } else {
        const uint32_t* ap = a2p + (((size_t)(b0+row)) << 9) + (klog - r1*64);
        S.a[0]=aload_u64(ap);   S.a[1]=aload_u64(ap+2);
        S.a[2]=aload_u64(ap+4); S.a[3]=aload_u64(ap+6);
      }
      const uint32_t* bp = wp + (size_t)row*K + klog;
      S.b0 = *(const uint4*)bp;
      S.b1 = *(const uint4*)(bp+4);
    }
  };

  auto commit = [&](SR* R, int r){
    const bool f32path = (r < r1) && (a1f != nullptr);
    #pragma unroll
    for (int q=0; q<2; ++q){
      SR& S = R[q];
      const int didx = (q==0) ? didx0 : didx1;
      union { ushort_t us[8]; bf16x8 v; } H, L, BH, BL;
      if (f32path){
        #pragma unroll
        for (int i=0;i<4;++i){
          uint32_t p0=(uint32_t)S.a[i], p1=(uint32_t)(S.a[i]>>32);
          float f0=__uint_as_float(p0), f1=__uint_as_float(p1);
          split2(f0, H.us[2*i],   L.us[2*i]);
          split2(f1, H.us[2*i+1], L.us[2*i+1]);
        }
      } else {
        #pragma unroll
        for (int i=0;i<4;++i){
          uint32_t p0=(uint32_t)S.a[i], p1=(uint32_t)(S.a[i]>>32);
          H.us[2*i]  =(ushort_t)p0; L.us[2*i]  =(ushort_t)(p0>>16);
          H.us[2*i+1]=(ushort_t)p1; L.us[2*i+1]=(ushort_t)(p1>>16);
        }
      }
      uint32_t bb[8] = {S.b0.x,S.b0.y,S.b0.z,S.b0.w,S.b1.x,S.b1.y,S.b1.z,S.b1.w};
      #pragma unroll
      for (int i=0;i<8;++i){ BH.us[i]=(ushort_t)bb[i]; BL.us[i]=(ushort_t)(bb[i]>>16); }
      *(bf16x8*)&sAh[didx] = H.v;
      *(bf16x8*)&sAl[didx] = L.v;
      *(bf16x8*)&sBh[didx] = BH.v;
      *(bf16x8*)&sBl[didx] = BL.v;
    }
  };

  auto mma = [&](){
    const int ju = km*4 + kh;
    bf16x8 ah[2], al[2];
    #pragma unroll
    for (int mm=0; mm<2; ++mm){
      int rowa = (mh*2+mm)*16 + lr;
      int idx = (rowa*8 + (ju ^ (rowa&7)))*8;
      ah[mm] = *(bf16x8*)&sAh[idx];
      al[mm] = *(bf16x8*)&sAl[idx];
    }
    #pragma unroll
    for (int nn=0; nn<4; ++nn){
      int rowb = nn*16 + lr;
      int idx = (rowb*8 + (ju ^ (rowb&7)))*8;
      bf16x8 bh = *(bf16x8*)&sBh[idx];
      bf16x8 bl = *(bf16x8*)&sBl[idx];
      #pragma unroll
      for (int mm=0; mm<2; ++mm){
        acc[mm][nn] = __builtin_amdgcn_mfma_f32_16x16x32_bf16(ah[mm], bh, acc[mm][nn],0,0,0);
        acc[mm][nn] = __builtin_amdgcn_mfma_f32_16x16x32_bf16(ah[mm], bl, acc[mm][nn],0,0,0);
        acc[mm][nn] = __builtin_amdgcn_mfma_f32_16x16x32_bf16(al[mm], bh, acc[mm][nn],0,0,0);
      }
    }
  };

  // main loop, register double-buffered staging
  SR R0[2], R1[2];
  issue(R0, 0);
  int r = 0;
  while (true){
    if (r+1 < nrounds) issue(R1, r+1);
    commit(R0, r);
    __syncthreads();
    mma();
    __syncthreads();
    if (++r >= nrounds) break;
    if (r+1 < nrounds) issue(R0, r+1);
    commit(R1, r);
    __syncthreads();
    mma();
    __syncthreads();
    if (++r >= nrounds) break;
  }

  // ---- cross-wave reduction (km pair) ----
  float* sR = (float*)lds;
  if (km == 1){
    #pragma unroll
    for (int mm=0; mm<2; ++mm)
      #pragma unroll
      for (int nn=0; nn<4; ++nn){
        int c = mm*4 + nn;
        *(f32x4*)&sR[mh*2048 + l*32 + (c ^ (l&7))*4] = acc[mm][nn];
      }
  }
  __syncthreads();
  if (km == 0){
    #pragma unroll
    for (int mm=0; mm<2; ++mm)
      #pragma unroll
      for (int nn=0; nn<4; ++nn){
        int c = mm*4 + nn;
        acc[mm][nn] += *(f32x4*)&sR[mh*2048 + l*32 + (c ^ (l&7))*4];
      }
    float bi = bias[       j0 + lr];
    float bf = bias[ 512 + j0 + lr];
    float bg = bias[1024 + j0 + lr];
    float bo = bias[1536 + j0 + lr];
    #pragma unroll
    for (int mm=0; mm<2; ++mm){
      #pragma unroll
      for (int q=0; q<4; ++q){
        int row = (mh*2+mm)*16 + kh*4 + q;
        float gi = acc[mm][0][q] + bi;
        float gf = acc[mm][1][q] + bf;
        float gg = acc[mm][2][q] + bg;
        float go = acc[mm][3][q] + bo;
        size_t gidx = (size_t)((b0+row)<<9) + j0 + lr;
        float cold = cbuf[gidx];
        float cn = sigf(gf)*cold + sigf(gi)*tanhfast(gg);
        cbuf[gidx] = cn;
        float hval = sigf(go)*tanhfast(cn);
        ushort_t hh2, hl2; split2(hval, hh2, hl2);
        astore_u32(&houtp[gidx], (uint32_t)hh2 | ((uint32_t)hl2 << 16));
      }
    }
  }
  __syncthreads();
}

// ---- phase bodies ----
__device__ __forceinline__ void do_enc(const KP& p, ushort_t* lds, int bid, int s){
  const int role = bid >> 8;
  const int tile = bid & 255;
  const int m = tile >> 5, nt = tile & 31;   // nt&7 == bid&7 -> XCD-affine weights
  const int b0 = m*64, j0 = nt*16;
  uint32_t* h0p[2] = { p.h0p0, p.h0p1 };
  uint32_t* h1p[2] = { p.h1p0, p.h1p1 };
  if (role == 0){
    if (s >= TT) return;
    const int t = s;
    cell_tile(lds, b0, j0,
      p.x + (size_t)t*IIN, nullptr, TT*IIN, 1,
      h0p[(t+1)&1],
      p.Wp + (size_t)nt*64*576, 576, 9,
      p.b0v, p.c0, h0p[t&1]);
  } else {
    if (s < 1) return;
    const int t = s-1;
    cell_tile(lds, b0, j0,
      nullptr, h0p[t&1], 512, 8,
      h1p[(t+1)&1],
      p.Wp + N0W + (size_t)nt*64*1024, 1024, 16,
      p.b1v, p.c1, h1p[t&1]);
  }
}

__device__ __forceinline__ void do_dec0(const KP& p, ushort_t* lds, int tile, int d, int p0){
  const int m = tile >> 5, nt = tile & 31;
  const int b0 = m*64, j0 = nt*16;
  uint32_t* h0p[2] = { p.h0p0, p.h0p1 };
  const uint32_t* w0 = p.Wp + (size_t)nt*64*576;
  if (d == 0)
    cell_tile(lds, b0, j0,
      p.x + (size_t)(TT-1)*IIN, nullptr, TT*IIN, 1,
      h0p[p0], w0, 576, 9,
      p.b0v, p.c0, h0p[1-p0]);
  else
    cell_tile(lds, b0, j0,
      nullptr, p.outp, 64, 1,
      h0p[p0], w0, 576, 9,
      p.b0v, p.c0, h0p[1-p0]);
}

__device__ __forceinline__ void do_dec1(const KP& p, ushort_t* lds, int tile, int p0, int p1){
  const int m = tile >> 5, nt = tile & 31;
  const int b0 = m*64, j0 = nt*16;
  uint32_t* h0p[2] = { p.h0p0, p.h0p1 };
  uint32_t* h1p[2] = { p.h1p0, p.h1p1 };
  cell_tile(lds, b0, j0,
    nullptr, h0p[1-p0], 512, 8,
    h1p[p1],
    p.Wp + N0W + (size_t)nt*64*1024, 1024, 16,
    p.b1v, p.c1, h1p[1-p1]);
}

__device__ __forceinline__ void do_lin(const KP& p, int bid, int d, int p1){
  uint32_t* h1p[2] = { p.h1p0, p.h1p1 };
  const uint32_t* hp = h1p[1-p1];
  int row = bid*4 + (threadIdx.x >> 6);
  int i   = threadIdx.x & 63;
  const uint32_t* hr = hp + ((size_t)row << 9);
  const float* wr = p.Wlin + (size_t)i*512;
  float ssum = 0.f;
  for (int k = 0; k < 512; k += 8){
    unsigned long long d0 = aload_u64(hr+k),   d1 = aload_u64(hr+k+2);
    unsigned long long d2 = aload_u64(hr+k+4), d3 = aload_u64(hr+k+6);
    unsigned long long dd[4] = {d0,d1,d2,d3};
    #pragma unroll
    for (int t2=0;t2<4;++t2){
      uint32_t q0=(uint32_t)dd[t2], q1=(uint32_t)(dd[t2]>>32);
      ssum += (bf2f((ushort_t)q0)+bf2f((ushort_t)(q0>>16))) * wr[k+t2*2];
      ssum += (bf2f((ushort_t)q1)+bf2f((ushort_t)(q1>>16))) * wr[k+t2*2+1];
    }
  }
  ssum += p.blin[i];
  p.out[(size_t)row*(NSTEPS*IIN) + d*IIN + i] = ssum;
  ushort_t oh, ol; split2(ssum, oh, ol);
  astore_u32(&p.outp[row*64 + i], (uint32_t)oh | ((uint32_t)ol<<16));
}

// ---- persistent kernel with hand-rolled grid barrier (no L2-flushing fences)
__global__ __launch_bounds__(256, 2)
void lstm_persist(KP p)
{
  const int bid = blockIdx.x;
  __shared__ ushort_t lds[16384];   // 32 KB
  int slot = 0;

  auto gbar = [&](){
    __syncthreads();   // all block stores issued+drained (vmcnt(0) before s_barrier)
    if (threadIdx.x == 0){
      __hip_atomic_fetch_add(&p.bar[slot], 1u, __ATOMIC_RELAXED, __HIP_MEMORY_SCOPE_AGENT);
      while (__hip_atomic_load(&p.bar[slot], __ATOMIC_RELAXED, __HIP_MEMORY_SCOPE_AGENT)
             < (uint32_t)NBLOCKS)
        __builtin_amdgcn_s_sleep(1);
    }
    __syncthreads();
    ++slot;
  };

  for (int s = 0; s <= TT; ++s){
    do_enc(p, lds, bid, s);
    gbar();
  }
  int p0 = 1, p1 = 1;
  for (int d = 0; d < NSTEPS; ++d){
    if (bid < 256) do_dec0(p, lds, bid, d, p0);
    gbar();
    if (bid >= 256) do_dec1(p, lds, bid & 255, p0, p1);
    gbar();
    if (bid < 128) do_lin(p, bid, d, p1);
    gbar();
    p0 ^= 1; p1 ^= 1;
  }
}

// ---- fallback per-step kernels (kernel boundaries provide coherence) ----
__global__ __launch_bounds__(256, 2)
void fb_enc(KP p, int s){ __shared__ ushort_t lds[16384]; do_enc(p, lds, blockIdx.x, s); }
__global__ __launch_bounds__(256, 2)
void fb_dec0(KP p, int d, int p0){ __shared__ ushort_t lds[16384]; do_dec0(p, lds, blockIdx.x, d, p0); }
__global__ __launch_bounds__(256, 2)
void fb_dec1(KP p, int p0, int p1){ __shared__ ushort_t lds[16384]; do_dec1(p, lds, blockIdx.x, p0, p1); }
__global__ __launch_bounds__(256)
void fb_lin(KP p, int d, int p1){ do_lin(p, blockIdx.x, d, p1); }

// ---- prep kernels ----
__global__ void bias_kernel(const float* a, const float* b, float* o){
  int i = blockIdx.x * 256 + threadIdx.x;
  if (i < G4) o[i] = a[i] + b[i];
}

__global__ void prep_w(const float* __restrict__ Wih0, const float* __restrict__ Whh0,
                       const float* __restrict__ Wih1, const float* __restrict__ Whh1,
                       uint32_t* __restrict__ Wp)
{
  size_t i = (size_t)blockIdx.x*256 + threadIdx.x;
  if (i >= NTW) return;
  float val;
  if (i < N0W){
    size_t e = i;
    int nt = (int)(e / (64*576)); int rem = (int)(e % (64*576));
    int cl = rem / 576; int k = rem % 576;
    int grow = (cl>>4)*512 + nt*16 + (cl&15);
    val = (k < 64) ? Wih0[(size_t)grow*64 + k] : Whh0[(size_t)grow*512 + (k-64)];
  } else {
    size_t e = i - N0W;
    int nt = (int)(e >> 16); int rem = (int)(e & 65535);   // 64*1024
    int cl = rem >> 10; int k = rem & 1023;
    int grow = (cl>>4)*512 + nt*16 + (cl&15);
    val = (k < 512) ? Wih1[(size_t)grow*512 + k] : Whh1[(size_t)grow*512 + (k-512)];
  }
  ushort_t h, lo2; split2(val, h, lo2);
  Wp[i] = (uint32_t)h | ((uint32_t)lo2 << 16);
}

extern "C" void kernel_launch(void* const* d_in, const int* in_sizes, int n_in,
                              void* d_out, int out_size, void* d_ws, size_t ws_size,
                              hipStream_t stream)
{
  const float* x     = (const float*)d_in[0];
  const float* W_ih0 = (const float*)d_in[1];
  const float* W_hh0 = (const float*)d_in[2];
  const float* b_ih0 = (const float*)d_in[3];
  const float* b_hh0 = (const float*)d_in[4];
  const float* W_ih1 = (const float*)d_in[5];
  const float* W_hh1 = (const float*)d_in[6];
  const float* b_ih1 = (const float*)d_in[7];
  const float* b_hh1 = (const float*)d_in[8];
  const float* W_lin = (const float*)d_in[9];
  const float* b_lin = (const float*)d_in[10];

  char* ws = (char*)d_ws;
  size_t off = 0;
  auto alloc = [&](size_t bytes){ size_t o = off; off += (bytes + 255) & ~(size_t)255; return o; };

  float* b0v = (float*)(ws + alloc(G4*4));
  float* b1v = (float*)(ws + alloc(G4*4));
  uint32_t* Wp = (uint32_t*)(ws + alloc(NTW*4));

  const size_t BH = (size_t)BSZ * HH;      // 262144
  // states: 4 packed h buffers + 2 f32 c buffers + packed out + barrier counters
  size_t statesBytes = 4*BH*4 + 2*BH*4 + (size_t)BSZ*IIN*4 + 512*4;
  char* states = ws + alloc(statesBytes);
  uint32_t* h0p0 = (uint32_t*)states;
  uint32_t* h0p1 = h0p0 + BH;
  uint32_t* h1p0 = h0p0 + 2*BH;
  uint32_t* h1p1 = h0p0 + 3*BH;
  float* c0 = (float*)(h0p0 + 4*BH);
  float* c1 = c0 + BH;
  uint32_t* outp = (uint32_t*)(c0 + 2*BH);
  uint32_t* bar  = outp + (size_t)BSZ*IIN;

  // ---- prep ----
  bias_kernel<<<(G4+255)/256, 256, 0, stream>>>(b_ih0, b_hh0, b0v);
  bias_kernel<<<(G4+255)/256, 256, 0, stream>>>(b_ih1, b_hh1, b1v);
  prep_w<<<(int)((NTW+255)/256), 256, 0, stream>>>(W_ih0, W_hh0, W_ih1, W_hh1, Wp);
  hipMemsetAsync(states, 0, statesBytes, stream);

  KP kp;
  kp.x = x; kp.Wp = Wp; kp.b0v = b0v; kp.b1v = b1v;
  kp.Wlin = W_lin; kp.blin = b_lin;
  kp.h0p0 = h0p0; kp.h0p1 = h0p1; kp.h1p0 = h1p0; kp.h1p1 = h1p1;
  kp.c0 = c0; kp.c1 = c1; kp.outp = outp;
  kp.out = (float*)d_out;
  kp.bar = bar;

  // ---- persistent cooperative kernel; fall back to per-step launches ----
  void* kargs[] = { &kp };
  hipError_t ce = hipLaunchCooperativeKernel((void*)lstm_persist,
                                             dim3(NBLOCKS), dim3(256), kargs, 0, stream);
  if (ce != hipSuccess){
    for (int s = 0; s <= TT; ++s)
      fb_enc<<<NBLOCKS, 256, 0, stream>>>(kp, s);
    int p0 = 1, p1 = 1;
    for (int d = 0; d < NSTEPS; ++d){
      fb_dec0<<<256, 256, 0, stream>>>(kp, d, p0);
      fb_dec1<<<256, 256, 0, stream>>>(kp, p0, p1);
      fb_lin<<<128, 256, 0, stream>>>(kp, d, p1);
      p0 ^= 1; p1 ^= 1;
    }
  }
}

// Round 5
// 13868.098 us; speedup vs baseline: 1.5756x; 1.0901x over previous
//
#include <hip/hip_runtime.h>
#include <stdint.h>

#define BSZ 512
#define TT  256
#define IIN 64
#define HH  512
#define G4  2048
#define NSTEPS 10
#define NBLOCKS 512

typedef unsigned short ushort_t;
typedef short bf16x8 __attribute__((ext_vector_type(8)));
typedef float f32x4  __attribute__((ext_vector_type(4)));

static constexpr size_t N0W = (size_t)G4 * 576;          // role0 weight elems
static constexpr size_t NTW = N0W + (size_t)G4 * 1024;   // + role1

__device__ __forceinline__ ushort_t f2bf(float f){
  union { float f; uint32_t u; } v; v.f = f;
  uint32_t u = v.u;
  return (ushort_t)((u + 0x7fffu + ((u >> 16) & 1u)) >> 16);
}
__device__ __forceinline__ float bf2f(ushort_t h){
  union { uint32_t u; float f; } v; v.u = ((uint32_t)h) << 16;
  return v.f;
}
__device__ __forceinline__ void split2(float f, ushort_t& h, ushort_t& l){
  h = f2bf(f); l = f2bf(f - bf2f(h));
}
__device__ __forceinline__ float sigf(float x){ return 1.0f/(1.0f+__expf(-x)); }
__device__ __forceinline__ float tanhfast(float x){ return 1.0f - 2.0f/(__expf(2.0f*x)+1.0f); }

// coherent (agent-scope, MALL-served) ops for cross-block state
__device__ __forceinline__ unsigned long long aload64(const ushort_t* p){
  return __hip_atomic_load((const unsigned long long*)(const void*)p,
                           __ATOMIC_RELAXED, __HIP_MEMORY_SCOPE_AGENT);
}
__device__ __forceinline__ void astore16(ushort_t* p, ushort_t v){
  __hip_atomic_store(p, v, __ATOMIC_RELAXED, __HIP_MEMORY_SCOPE_AGENT);
}

struct KP {
  const float* x;
  const ushort_t *Wh, *Wl;              // weight hi/lo planes (tile-packed)
  const float *b0v, *b1v;
  const float *Wlin, *blin;
  ushort_t *h0h0, *h0h1, *h0l0, *h0l1;  // h hi/lo plane double-buffers
  ushort_t *h1h0, *h1h1, *h1l0, *h1l1;
  float *c0, *c1;                       // fallback-path c only
  ushort_t *outh, *outl;                // decoder feedback planes
  float* out;
  uint32_t *bar, *rel;
};

// ---------------------------------------------------------------------------
// LSTM cell tile: 64 batch rows (b0..) x (4 gates x 16 h-cols at j0..).
// Waves: w = (mh<<1)|km (km = K-half, mh = 32-row half). All operands loaded
// DIRECTLY into MFMA-layout registers: A (h) via u64 agent-atomic loads from
// hi/lo planes; B (weights) via plain bf16x8 loads (L2-resident, XCD-affine).
// No LDS staging, no K-loop barriers. LDS only for the km-pair reduction.
// c state in registers (creg) for the persistent path; memory (cbuf) fallback.
// ---------------------------------------------------------------------------
__device__ __forceinline__ void cell_tile(
  int b0, int j0,
  const float* a1f, const ushort_t* a1h, const ushort_t* a1l, int a1s, int r1,
  const ushort_t* a2h, const ushort_t* a2l,
  const ushort_t* wbh, const ushort_t* wbl, int K, int nr,
  const float* bias, float* creg, float* cbuf,
  ushort_t* houth, ushort_t* houtl)
{
  __shared__ float sR[4096];   // 16 KB reduction buffer

  const int tid = threadIdx.x;
  const int w  = tid >> 6;
  const int l  = tid & 63;
  const int km = w & 1;
  const int mh = w >> 1;
  const int lr = l & 15;
  const int kh = l >> 4;
  const int kofs = km*32 + kh*8;
  const int rowa0 = b0 + mh*32 + lr;
  const int rowa1 = rowa0 + 16;

  f32x4 acc[2][4];
  #pragma unroll
  for (int mm=0; mm<2; ++mm)
    #pragma unroll
    for (int nn=0; nn<4; ++nn)
      acc[mm][nn] = (f32x4){0.f,0.f,0.f,0.f};

  const ushort_t* wb0 = wbh + (size_t)lr*K;
  const ushort_t* wl0 = wbl + (size_t)lr*K;

  // rounds [0, r1): A from a1 (f32 x, or hi/lo planes)
  for (int r = 0; r < r1; ++r){
    const int klog = r*64 + kofs;
    bf16x8 ah0, al0, ah1, al1;
    if (a1f){
      const float* p0 = a1f + (size_t)rowa0*a1s + klog;
      const float* p1 = a1f + (size_t)rowa1*a1s + klog;
      f32x4 u0 = *(const f32x4*)p0, u1 = *(const f32x4*)(p0+4);
      f32x4 v0 = *(const f32x4*)p1, v1 = *(const f32x4*)(p1+4);
      union { ushort_t us[8]; bf16x8 v; } H0,L0,H1,L1;
      #pragma unroll
      for (int j=0;j<4;++j){
        split2(u0[j], H0.us[j],   L0.us[j]);
        split2(u1[j], H0.us[4+j], L0.us[4+j]);
        split2(v0[j], H1.us[j],   L1.us[j]);
        split2(v1[j], H1.us[4+j], L1.us[4+j]);
      }
      ah0=H0.v; al0=L0.v; ah1=H1.v; al1=L1.v;
    } else {
      union { unsigned long long q[2]; bf16x8 v; } t0,t1,t2,t3;
      const ushort_t* ph0 = a1h + (size_t)rowa0*a1s + klog;
      const ushort_t* pl0 = a1l + (size_t)rowa0*a1s + klog;
      const ushort_t* ph1 = a1h + (size_t)rowa1*a1s + klog;
      const ushort_t* pl1 = a1l + (size_t)rowa1*a1s + klog;
      t0.q[0]=aload64(ph0); t0.q[1]=aload64(ph0+4);
      t1.q[0]=aload64(pl0); t1.q[1]=aload64(pl0+4);
      t2.q[0]=aload64(ph1); t2.q[1]=aload64(ph1+4);
      t3.q[0]=aload64(pl1); t3.q[1]=aload64(pl1+4);
      ah0=t0.v; al0=t1.v; ah1=t2.v; al1=t3.v;
    }
    #pragma unroll
    for (int nn=0; nn<4; ++nn){
      bf16x8 bh = *(const bf16x8*)&wb0[(size_t)nn*16*K + klog];
      bf16x8 bl = *(const bf16x8*)&wl0[(size_t)nn*16*K + klog];
      acc[0][nn] = __builtin_amdgcn_mfma_f32_16x16x32_bf16(ah0, bh, acc[0][nn],0,0,0);
      acc[1][nn] = __builtin_amdgcn_mfma_f32_16x16x32_bf16(ah1, bh, acc[1][nn],0,0,0);
      acc[0][nn] = __builtin_amdgcn_mfma_f32_16x16x32_bf16(ah0, bl, acc[0][nn],0,0,0);
      acc[1][nn] = __builtin_amdgcn_mfma_f32_16x16x32_bf16(ah1, bl, acc[1][nn],0,0,0);
      acc[0][nn] = __builtin_amdgcn_mfma_f32_16x16x32_bf16(al0, bh, acc[0][nn],0,0,0);
      acc[1][nn] = __builtin_amdgcn_mfma_f32_16x16x32_bf16(al1, bh, acc[1][nn],0,0,0);
    }
  }

  // rounds [r1, nr): A from a2 planes (stride 512)
  for (int r = r1; r < nr; ++r){
    const int klog = r*64 + kofs;
    const int k2 = klog - r1*64;
    union { unsigned long long q[2]; bf16x8 v; } t0,t1,t2,t3;
    const ushort_t* ph0 = a2h + ((size_t)rowa0 << 9) + k2;
    const ushort_t* pl0 = a2l + ((size_t)rowa0 << 9) + k2;
    const ushort_t* ph1 = a2h + ((size_t)rowa1 << 9) + k2;
    const ushort_t* pl1 = a2l + ((size_t)rowa1 << 9) + k2;
    t0.q[0]=aload64(ph0); t0.q[1]=aload64(ph0+4);
    t1.q[0]=aload64(pl0); t1.q[1]=aload64(pl0+4);
    t2.q[0]=aload64(ph1); t2.q[1]=aload64(ph1+4);
    t3.q[0]=aload64(pl1); t3.q[1]=aload64(pl1+4);
    bf16x8 ah0=t0.v, al0=t1.v, ah1=t2.v, al1=t3.v;
    #pragma unroll
    for (int nn=0; nn<4; ++nn){
      bf16x8 bh = *(const bf16x8*)&wb0[(size_t)nn*16*K + klog];
      bf16x8 bl = *(const bf16x8*)&wl0[(size_t)nn*16*K + klog];
      acc[0][nn] = __builtin_amdgcn_mfma_f32_16x16x32_bf16(ah0, bh, acc[0][nn],0,0,0);
      acc[1][nn] = __builtin_amdgcn_mfma_f32_16x16x32_bf16(ah1, bh, acc[1][nn],0,0,0);
      acc[0][nn] = __builtin_amdgcn_mfma_f32_16x16x32_bf16(ah0, bl, acc[0][nn],0,0,0);
      acc[1][nn] = __builtin_amdgcn_mfma_f32_16x16x32_bf16(ah1, bl, acc[1][nn],0,0,0);
      acc[0][nn] = __builtin_amdgcn_mfma_f32_16x16x32_bf16(al0, bh, acc[0][nn],0,0,0);
      acc[1][nn] = __builtin_amdgcn_mfma_f32_16x16x32_bf16(al1, bh, acc[1][nn],0,0,0);
    }
  }

  // ---- km-pair reduction via LDS ----
  if (km == 1){
    #pragma unroll
    for (int mm=0; mm<2; ++mm)
      #pragma unroll
      for (int nn=0; nn<4; ++nn){
        int c = mm*4 + nn;
        *(f32x4*)&sR[mh*2048 + l*32 + (c ^ (l&7))*4] = acc[mm][nn];
      }
  }
  __syncthreads();
  if (km == 0){
    #pragma unroll
    for (int mm=0; mm<2; ++mm)
      #pragma unroll
      for (int nn=0; nn<4; ++nn){
        int c = mm*4 + nn;
        acc[mm][nn] += *(f32x4*)&sR[mh*2048 + l*32 + (c ^ (l&7))*4];
      }
    float bi = bias[       j0 + lr];
    float bf = bias[ 512 + j0 + lr];
    float bg = bias[1024 + j0 + lr];
    float bo = bias[1536 + j0 + lr];
    #pragma unroll
    for (int mm=0; mm<2; ++mm){
      #pragma unroll
      for (int q=0; q<4; ++q){
        int row = (mh*2+mm)*16 + kh*4 + q;
        float gi = acc[mm][0][q] + bi;
        float gf = acc[mm][1][q] + bf;
        float gg = acc[mm][2][q] + bg;
        float go = acc[mm][3][q] + bo;
        size_t gidx = (size_t)((b0+row)<<9) + j0 + lr;
        float cold = cbuf ? cbuf[gidx] : creg[mm*4+q];
        float cn = sigf(gf)*cold + sigf(gi)*tanhfast(gg);
        if (cbuf) cbuf[gidx] = cn; else creg[mm*4+q] = cn;
        float hval = sigf(go)*tanhfast(cn);
        ushort_t hh2, hl2; split2(hval, hh2, hl2);
        astore16(&houth[gidx], hh2);
        astore16(&houtl[gidx], hl2);
      }
    }
  }
  __syncthreads();
}

// ---- phase bodies ----
__device__ __forceinline__ void do_enc(const KP& p, int bid, int s,
                                       float* creg, float* cb0, float* cb1){
  const int role = bid >> 8;
  const int tile = bid & 255;
  const int m = tile >> 5, nt = tile & 31;   // nt&7 == bid&7 -> XCD-affine weights
  const int b0 = m*64, j0 = nt*16;
  const ushort_t* h0h[2] = { p.h0h0, p.h0h1 };
  const ushort_t* h0l[2] = { p.h0l0, p.h0l1 };
  const ushort_t* h1h[2] = { p.h1h0, p.h1h1 };
  const ushort_t* h1l[2] = { p.h1l0, p.h1l1 };
  ushort_t* h0hw[2] = { p.h0h0, p.h0h1 };
  ushort_t* h0lw[2] = { p.h0l0, p.h0l1 };
  ushort_t* h1hw[2] = { p.h1h0, p.h1h1 };
  ushort_t* h1lw[2] = { p.h1l0, p.h1l1 };
  if (role == 0){
    if (s >= TT) return;
    const int t = s;
    cell_tile(b0, j0,
      p.x + (size_t)t*IIN, nullptr, nullptr, TT*IIN, 1,
      h0h[(t+1)&1], h0l[(t+1)&1],
      p.Wh + (size_t)nt*64*576, p.Wl + (size_t)nt*64*576, 576, 9,
      p.b0v, creg, cb0, h0hw[t&1], h0lw[t&1]);
  } else {
    if (s < 1) return;
    const int t = s-1;
    cell_tile(b0, j0,
      nullptr, h0h[t&1], h0l[t&1], 512, 8,
      h1h[(t+1)&1], h1l[(t+1)&1],
      p.Wh + N0W + (size_t)nt*64*1024, p.Wl + N0W + (size_t)nt*64*1024, 1024, 16,
      p.b1v, creg, cb1, h1hw[t&1], h1lw[t&1]);
  }
}

__device__ __forceinline__ void do_dec0(const KP& p, int tile, int d, int p0,
                                        float* creg, float* cb0){
  const int m = tile >> 5, nt = tile & 31;
  const int b0 = m*64, j0 = nt*16;
  const ushort_t* h0h[2] = { p.h0h0, p.h0h1 };
  const ushort_t* h0l[2] = { p.h0l0, p.h0l1 };
  ushort_t* h0hw[2] = { p.h0h0, p.h0h1 };
  ushort_t* h0lw[2] = { p.h0l0, p.h0l1 };
  const ushort_t* w0h = p.Wh + (size_t)nt*64*576;
  const ushort_t* w0l = p.Wl + (size_t)nt*64*576;
  if (d == 0)
    cell_tile(b0, j0,
      p.x + (size_t)(TT-1)*IIN, nullptr, nullptr, TT*IIN, 1,
      h0h[p0], h0l[p0], w0h, w0l, 576, 9,
      p.b0v, creg, cb0, h0hw[1-p0], h0lw[1-p0]);
  else
    cell_tile(b0, j0,
      nullptr, p.outh, p.outl, 64, 1,
      h0h[p0], h0l[p0], w0h, w0l, 576, 9,
      p.b0v, creg, cb0, h0hw[1-p0], h0lw[1-p0]);
}

__device__ __forceinline__ void do_dec1(const KP& p, int tile, int p0, int p1,
                                        float* creg, float* cb1){
  const int m = tile >> 5, nt = tile & 31;
  const int b0 = m*64, j0 = nt*16;
  const ushort_t* h0h[2] = { p.h0h0, p.h0h1 };
  const ushort_t* h0l[2] = { p.h0l0, p.h0l1 };
  const ushort_t* h1h[2] = { p.h1h0, p.h1h1 };
  const ushort_t* h1l[2] = { p.h1l0, p.h1l1 };
  ushort_t* h1hw[2] = { p.h1h0, p.h1h1 };
  ushort_t* h1lw[2] = { p.h1l0, p.h1l1 };
  cell_tile(b0, j0,
    nullptr, h0h[1-p0], h0l[1-p0], 512, 8,
    h1h[p1], h1l[p1],
    p.Wh + N0W + (size_t)nt*64*1024, p.Wl + N0W + (size_t)nt*64*1024, 1024, 16,
    p.b1v, creg, cb1, h1hw[1-p1], h1lw[1-p1]);
}

__device__ __forceinline__ void do_lin(const KP& p, int bid, int d, int p1){
  const ushort_t* h1h[2] = { p.h1h0, p.h1h1 };
  const ushort_t* h1l[2] = { p.h1l0, p.h1l1 };
  const ushort_t* hh = h1h[1-p1];
  const ushort_t* hl = h1l[1-p1];
  int row = bid*4 + (threadIdx.x >> 6);
  int i   = threadIdx.x & 63;
  const ushort_t* hr = hh + ((size_t)row << 9);
  const ushort_t* lp = hl + ((size_t)row << 9);
  const float* wr = p.Wlin + (size_t)i*512;
  float ssum = 0.f;
  for (int k = 0; k < 512; k += 8){
    union { unsigned long long q[2]; ushort_t us[8]; } H, L;
    H.q[0]=aload64(hr+k); H.q[1]=aload64(hr+k+4);
    L.q[0]=aload64(lp+k); L.q[1]=aload64(lp+k+4);
    #pragma unroll
    for (int j=0;j<8;++j)
      ssum += (bf2f(H.us[j]) + bf2f(L.us[j])) * wr[k+j];
  }
  ssum += p.blin[i];
  p.out[(size_t)row*(NSTEPS*IIN) + d*IIN + i] = ssum;
  ushort_t oh, ol; split2(ssum, oh, ol);
  astore16(&p.outh[row*64 + i], oh);
  astore16(&p.outl[row*64 + i], ol);
}

// ---- persistent kernel with release-broadcast grid barrier (no L2 flush) ----
__global__ __launch_bounds__(256, 2)
void lstm_persist(KP p)
{
  const int bid = blockIdx.x;
  float creg[8];
  #pragma unroll
  for (int i=0;i<8;++i) creg[i] = 0.f;

  int slot = 0;
  auto gbar = [&](){
    __syncthreads();   // drains this block's stores (vmcnt 0 before s_barrier)
    if (threadIdx.x == 0){
      uint32_t old = __hip_atomic_fetch_add(&p.bar[slot], 1u, __ATOMIC_RELAXED,
                                            __HIP_MEMORY_SCOPE_AGENT);
      if (old == (uint32_t)(NBLOCKS-1)){
        __hip_atomic_store(&p.rel[slot], 1u, __ATOMIC_RELAXED, __HIP_MEMORY_SCOPE_AGENT);
      } else {
        while (!__hip_atomic_load(&p.rel[slot], __ATOMIC_RELAXED, __HIP_MEMORY_SCOPE_AGENT))
          __builtin_amdgcn_s_sleep(1);
      }
    }
    __syncthreads();
    ++slot;
  };

  for (int s = 0; s <= TT; ++s){
    do_enc(p, bid, s, creg, nullptr, nullptr);
    gbar();
  }
  int p0 = 1, p1 = 1;
  for (int d = 0; d < NSTEPS; ++d){
    if (bid < 256) do_dec0(p, bid, d, p0, creg, nullptr);
    gbar();
    if (bid >= 256) do_dec1(p, bid & 255, p0, p1, creg, nullptr);
    gbar();
    if (bid < 128) do_lin(p, bid, d, p1);
    gbar();
    p0 ^= 1; p1 ^= 1;
  }
}

// ---- fallback per-step kernels (kernel boundaries give coherence; c in mem) ----
__global__ __launch_bounds__(256, 2)
void fb_enc(KP p, int s){ do_enc(p, blockIdx.x, s, nullptr, p.c0, p.c1); }
__global__ __launch_bounds__(256, 2)
void fb_dec0(KP p, int d, int p0){ do_dec0(p, blockIdx.x, d, p0, nullptr, p.c0); }
__global__ __launch_bounds__(256, 2)
void fb_dec1(KP p, int p0, int p1){ do_dec1(p, blockIdx.x, p0, p1, nullptr, p.c1); }
__global__ __launch_bounds__(256)
void fb_lin(KP p, int d, int p1){ do_lin(p, blockIdx.x, d, p1); }

// ---- prep kernels ----
__global__ void bias_kernel(const float* a, const float* b, float* o){
  int i = blockIdx.x * 256 + threadIdx.x;
  if (i < G4) o[i] = a[i] + b[i];
}

__global__ void prep_w(const float* __restrict__ Wih0, const float* __restrict__ Whh0,
                       const float* __restrict__ Wih1, const float* __restrict__ Whh1,
                       ushort_t* __restrict__ Wh, ushort_t* __restrict__ Wl)
{
  size_t i = (size_t)blockIdx.x*256 + threadIdx.x;
  if (i >= NTW) return;
  float val;
  if (i < N0W){
    size_t e = i;
    int nt = (int)(e / (64*576)); int rem = (int)(e % (64*576));
    int cl = rem / 576; int k = rem % 576;
    int grow = (cl>>4)*512 + nt*16 + (cl&15);
    val = (k < 64) ? Wih0[(size_t)grow*64 + k] : Whh0[(size_t)grow*512 + (k-64)];
  } else {
    size_t e = i - N0W;
    int nt = (int)(e >> 16); int rem = (int)(e & 65535);   // 64*1024
    int cl = rem >> 10; int k = rem & 1023;
    int grow = (cl>>4)*512 + nt*16 + (cl&15);
    val = (k < 512) ? Wih1[(size_t)grow*512 + k] : Whh1[(size_t)grow*512 + (k-512)];
  }
  ushort_t h, lo2; split2(val, h, lo2);
  Wh[i] = h; Wl[i] = lo2;
}

extern "C" void kernel_launch(void* const* d_in, const int* in_sizes, int n_in,
                              void* d_out, int out_size, void* d_ws, size_t ws_size,
                              hipStream_t stream)
{
  const float* x     = (const float*)d_in[0];
  const float* W_ih0 = (const float*)d_in[1];
  const float* W_hh0 = (const float*)d_in[2];
  const float* b_ih0 = (const float*)d_in[3];
  const float* b_hh0 = (const float*)d_in[4];
  const float* W_ih1 = (const float*)d_in[5];
  const float* W_hh1 = (const float*)d_in[6];
  const float* b_ih1 = (const float*)d_in[7];
  const float* b_hh1 = (const float*)d_in[8];
  const float* W_lin = (const float*)d_in[9];
  const float* b_lin = (const float*)d_in[10];

  char* ws = (char*)d_ws;
  size_t off = 0;
  auto alloc = [&](size_t bytes){ size_t o = off; off += (bytes + 255) & ~(size_t)255; return o; };

  float* b0v = (float*)(ws + alloc(G4*4));
  float* b1v = (float*)(ws + alloc(G4*4));
  ushort_t* Wh = (ushort_t*)(ws + alloc(NTW*2));
  ushort_t* Wl = (ushort_t*)(ws + alloc(NTW*2));

  const size_t BH = (size_t)BSZ * HH;      // 262144
  // states (memset together): 8 h-planes + 2 f32 c (fallback) + out planes + bar/rel
  size_t statesBytes = 8*BH*2 + 2*BH*4 + 2*(size_t)BSZ*IIN*2 + 2*1024*4;
  char* states = ws + alloc(statesBytes);
  ushort_t* hb = (ushort_t*)states;
  ushort_t* h0h0 = hb;            ushort_t* h0h1 = hb + BH;
  ushort_t* h0l0 = hb + 2*BH;     ushort_t* h0l1 = hb + 3*BH;
  ushort_t* h1h0 = hb + 4*BH;     ushort_t* h1h1 = hb + 5*BH;
  ushort_t* h1l0 = hb + 6*BH;     ushort_t* h1l1 = hb + 7*BH;
  float* c0 = (float*)(states + 8*BH*2);
  float* c1 = c0 + BH;
  ushort_t* outh = (ushort_t*)(states + 8*BH*2 + 2*BH*4);
  ushort_t* outl = outh + (size_t)BSZ*IIN;
  uint32_t* bar = (uint32_t*)(states + 8*BH*2 + 2*BH*4 + 2*(size_t)BSZ*IIN*2);
  uint32_t* rel = bar + 1024;

  // ---- prep ----
  bias_kernel<<<(G4+255)/256, 256, 0, stream>>>(b_ih0, b_hh0, b0v);
  bias_kernel<<<(G4+255)/256, 256, 0, stream>>>(b_ih1, b_hh1, b1v);
  prep_w<<<(int)((NTW+255)/256), 256, 0, stream>>>(W_ih0, W_hh0, W_ih1, W_hh1, Wh, Wl);
  hipMemsetAsync(states, 0, statesBytes, stream);

  KP kp;
  kp.x = x; kp.Wh = Wh; kp.Wl = Wl; kp.b0v = b0v; kp.b1v = b1v;
  kp.Wlin = W_lin; kp.blin = b_lin;
  kp.h0h0 = h0h0; kp.h0h1 = h0h1; kp.h0l0 = h0l0; kp.h0l1 = h0l1;
  kp.h1h0 = h1h0; kp.h1h1 = h1h1; kp.h1l0 = h1l0; kp.h1l1 = h1l1;
  kp.c0 = c0; kp.c1 = c1; kp.outh = outh; kp.outl = outl;
  kp.out = (float*)d_out;
  kp.bar = bar; kp.rel = rel;

  // ---- persistent cooperative kernel; fall back to per-step launches ----
  void* kargs[] = { &kp };
  hipError_t ce = hipLaunchCooperativeKernel((void*)lstm_persist,
                                             dim3(NBLOCKS), dim3(256), kargs, 0, stream);
  if (ce != hipSuccess){
    for (int s = 0; s <= TT; ++s)
      fb_enc<<<NBLOCKS, 256, 0, stream>>>(kp, s);
    int p0 = 1, p1 = 1;
    for (int d = 0; d < NSTEPS; ++d){
      fb_dec0<<<256, 256, 0, stream>>>(kp, d, p0);
      fb_dec1<<<256, 256, 0, stream>>>(kp, p0, p1);
      fb_lin<<<128, 256, 0, stream>>>(kp, d, p1);
      p0 ^= 1; p1 ^= 1;
    }
  }
}

// Round 6
// 10264.677 us; speedup vs baseline: 2.1286x; 1.3511x over previous
//
#include <hip/hip_runtime.h>
#include <stdint.h>

#define BSZ 512
#define TT  256
#define IIN 64
#define HH  512
#define NSTEPS 10
#define NBLOCKS 512

typedef unsigned short ushort_t;
typedef short bf16x8 __attribute__((ext_vector_type(8)));
typedef float f32x4  __attribute__((ext_vector_type(4)));

static constexpr size_t W0TILE = 256*576;        // role0 per-n-tile elems
static constexpr size_t W1TILE = 256*1024;       // role1
static constexpr size_t N0W = 8*W0TILE;          // 1,179,648
static constexpr size_t NTW = N0W + 8*W1TILE;    // + 2,097,152

__device__ __forceinline__ ushort_t f2bf(float f){
  union { float f; uint32_t u; } v; v.f = f;
  uint32_t u = v.u;
  return (ushort_t)((u + 0x7fffu + ((u >> 16) & 1u)) >> 16);
}
__device__ __forceinline__ float bf2f(ushort_t h){
  union { uint32_t u; float f; } v; v.u = ((uint32_t)h) << 16;
  return v.f;
}
__device__ __forceinline__ void split2(float f, ushort_t& h, ushort_t& l){
  h = f2bf(f); l = f2bf(f - bf2f(h));
}
__device__ __forceinline__ float sigf(float x){ return 1.0f/(1.0f+__expf(-x)); }
__device__ __forceinline__ float tanhfast(float x){ return 1.0f - 2.0f/(__expf(2.0f*x)+1.0f); }

// agent-scope (device-coherent, MALL-served) ops for cross-block state
__device__ __forceinline__ unsigned long long aload64(const uint32_t* p){
  return __hip_atomic_load((const unsigned long long*)(const void*)p,
                           __ATOMIC_RELAXED, __HIP_MEMORY_SCOPE_AGENT);
}
__device__ __forceinline__ void astore32(uint32_t* p, uint32_t v){
  __hip_atomic_store(p, v, __ATOMIC_RELAXED, __HIP_MEMORY_SCOPE_AGENT);
}

__device__ __forceinline__ int get_xcd(){
  unsigned v;
  asm volatile("s_getreg_b32 %0, hwreg(HW_REG_XCC_ID)" : "=s"(v));
  return (int)(v & 7);
}

struct KP {
  const float* x;
  const ushort_t *Wh, *Wl;        // packed weight hi/lo planes (tile layout)
  const float *b0v, *b1v;
  const float *Wlin, *blin;
  uint32_t *h0a, *h0b, *h1a, *h1b;  // packed h (hi | lo<<16) double buffers
  float *c0m, *c1m;               // fallback-path c
  uint32_t *outp;                 // packed decoder feedback
  float* out;
  uint32_t *bar, *rel, *assign;
};

// ---------------------------------------------------------------------------
// LDS A-tile layout: chunk c (32 k) x row r (0..15): 128B = 8 units of 16B.
// hi parts at logical u=0..3, lo at 4..7; physical slot (bank-spread both for
// writes across chunks and reads across rows):
//   hi: (u | ((c&1)<<2)) ^ (r&7)     lo: (u | (((c&1)^1)<<2)) ^ (r&7)
// ---------------------------------------------------------------------------
__device__ __forceinline__ int lds_base(int c, int r){ return (c*16 + r)*64; }

__device__ __forceinline__ void stage_packed(ushort_t* lds, const uint32_t* src,
    int rowbase, int stride, int lognu, int cbase)
{
  const int nunits = 1 << lognu;
  const int ntasks = nunits << 4;
  for (int tsk = threadIdx.x; tsk < ntasks; tsk += 256){
    const int r  = tsk >> lognu;
    const int uk = tsk & (nunits-1);
    const uint32_t* sp = src + (size_t)(rowbase + r)*stride + uk*8;
    unsigned long long qq[4];
    qq[0]=aload64(sp); qq[1]=aload64(sp+2); qq[2]=aload64(sp+4); qq[3]=aload64(sp+6);
    union { ushort_t us[8]; bf16x8 v; } H, L;
    #pragma unroll
    for (int i2=0;i2<4;++i2){
      uint32_t a2 = (uint32_t)qq[i2], b2 = (uint32_t)(qq[i2]>>32);
      H.us[2*i2]   = (ushort_t)a2;  L.us[2*i2]   = (ushort_t)(a2>>16);
      H.us[2*i2+1] = (ushort_t)b2;  L.us[2*i2+1] = (ushort_t)(b2>>16);
    }
    const int c = cbase + (uk >> 2);
    const int u = uk & 3;
    const int sh = (u | ((c&1)<<2)) ^ (r&7);
    const int sl = (u | (((c&1)^1)<<2)) ^ (r&7);
    *(bf16x8*)&lds[lds_base(c,r) + sh*8] = H.v;
    *(bf16x8*)&lds[lds_base(c,r) + sl*8] = L.v;
  }
}

__device__ __forceinline__ void stage_f32(ushort_t* lds, const float* src,
    int rowbase, int stride, int cbase)   // always 64 k (8 units/row)
{
  const int tsk = threadIdx.x;
  if (tsk < 128){
    const int r = tsk >> 3, uk = tsk & 7;
    const float* sp = src + (size_t)(rowbase + r)*stride + uk*8;
    f32x4 v0 = *(const f32x4*)sp, v1 = *(const f32x4*)(sp+4);
    union { ushort_t us[8]; bf16x8 v; } H, L;
    #pragma unroll
    for (int i2=0;i2<4;++i2){
      split2(v0[i2], H.us[i2],   L.us[i2]);
      split2(v1[i2], H.us[4+i2], L.us[4+i2]);
    }
    const int c = cbase + (uk >> 2);
    const int u = uk & 3;
    const int sh = (u | ((c&1)<<2)) ^ (r&7);
    const int sl = (u | (((c&1)^1)<<2)) ^ (r&7);
    *(bf16x8*)&lds[lds_base(c,r) + sh*8] = H.v;
    *(bf16x8*)&lds[lds_base(c,r) + sl*8] = L.v;
  }
}

// ---------------------------------------------------------------------------
// Compute: block tile = 16 batch rows x 256 gate-cols (4 gates x 64 h-cols).
// Wave w owns h-cols [w*16, w*16+16) x all 4 gates (subtile s = gate s).
// A from LDS (staged), B direct from L2-resident packed weights:
//   B layout: [chunk c][cl 0..255][ksub 0..3][8 elems], fully coalesced.
// Full K accumulated per wave -> no cross-wave reduction. Pointwise in-reg.
// ---------------------------------------------------------------------------
__device__ __forceinline__ void cell_compute(const ushort_t* lds,
    const ushort_t* __restrict__ wh, const ushort_t* __restrict__ wl, int nch,
    int m, int n, const float* bias, float* c4, float* cmem, uint32_t* houtp)
{
  const int tid = threadIdx.x;
  const int w = tid >> 6, l = tid & 63;
  const int lr = l & 15, kq = l >> 4;
  f32x4 acc[4];
  #pragma unroll
  for (int s=0;s<4;++s) acc[s] = (f32x4){0.f,0.f,0.f,0.f};

  const int clb = w*64 + lr;
  for (int c = 0; c < nch; ++c){
    const int shi = (kq | ((c&1)<<2)) ^ (lr&7);
    const int slo = (kq | (((c&1)^1)<<2)) ^ (lr&7);
    bf16x8 ah = *(const bf16x8*)&lds[lds_base(c,lr) + shi*8];
    bf16x8 al = *(const bf16x8*)&lds[lds_base(c,lr) + slo*8];
    #pragma unroll
    for (int s=0;s<4;++s){
      size_t bo = ((size_t)(c*256 + clb + s*16))*32 + kq*8;
      bf16x8 bh = *(const bf16x8*)&wh[bo];
      bf16x8 bl = *(const bf16x8*)&wl[bo];
      acc[s] = __builtin_amdgcn_mfma_f32_16x16x32_bf16(ah, bh, acc[s],0,0,0);
      acc[s] = __builtin_amdgcn_mfma_f32_16x16x32_bf16(ah, bl, acc[s],0,0,0);
      acc[s] = __builtin_amdgcn_mfma_f32_16x16x32_bf16(al, bh, acc[s],0,0,0);
    }
  }

  const int j = n*64 + w*16 + lr;
  const float bi = bias[j], bf = bias[512+j], bg = bias[1024+j], bo2 = bias[1536+j];
  #pragma unroll
  for (int q=0;q<4;++q){
    const int row = m*16 + kq*4 + q;
    float gi = acc[0][q]+bi, gf = acc[1][q]+bf, gg = acc[2][q]+bg, go = acc[3][q]+bo2;
    const size_t cidx = ((size_t)row << 9) + j;
    float cold = cmem ? cmem[cidx] : c4[q];
    float cn = sigf(gf)*cold + sigf(gi)*tanhfast(gg);
    if (cmem) cmem[cidx] = cn; else c4[q] = cn;
    float hv = sigf(go)*tanhfast(cn);
    ushort_t hh2, hl2; split2(hv, hh2, hl2);
    astore32(&houtp[cidx], (uint32_t)hh2 | ((uint32_t)hl2 << 16));
  }
}

// ---- phase bodies ----
__device__ __forceinline__ void role0_step(const KP& p, ushort_t* lds, int m, int n,
    const float* xsrc, const uint32_t* osrc,
    const uint32_t* h0r, uint32_t* h0w, float* c4, float* cmem)
{
  if (xsrc) stage_f32(lds, xsrc, m*16, TT*IIN, 0);
  else      stage_packed(lds, osrc, m*16, 64, 3, 0);
  stage_packed(lds, h0r, m*16, 512, 6, 2);
  __syncthreads();
  cell_compute(lds, p.Wh + (size_t)n*W0TILE, p.Wl + (size_t)n*W0TILE, 18,
               m, n, p.b0v, c4, cmem, h0w);
}

__device__ __forceinline__ void role1_step(const KP& p, ushort_t* lds, int m, int n,
    const uint32_t* h0cur, const uint32_t* h1r, uint32_t* h1w, float* c4, float* cmem)
{
  stage_packed(lds, h0cur, m*16, 512, 6, 0);
  stage_packed(lds, h1r,   m*16, 512, 6, 16);
  __syncthreads();
  cell_compute(lds, p.Wh + N0W + (size_t)n*W1TILE, p.Wl + N0W + (size_t)n*W1TILE, 32,
               m, n, p.b1v, c4, cmem, h1w);
}

__device__ __forceinline__ void lin_step(const KP& p, ushort_t* lds, int m, int d,
                                         const uint32_t* h1cur)
{
  float* lf = (float*)lds;                 // [16][512] f32 = 32 KB
  const int r0 = m*16;
  for (int tsk = threadIdx.x; tsk < 4096; tsk += 256){
    const int r = tsk >> 8, e2 = (tsk & 255)*2;
    unsigned long long q = aload64(h1cur + (size_t)(r0+r)*512 + e2);
    uint32_t a2 = (uint32_t)q, b2 = (uint32_t)(q>>32);
    lf[r*512 + e2]     = bf2f((ushort_t)a2) + bf2f((ushort_t)(a2>>16));
    lf[r*512 + e2 + 1] = bf2f((ushort_t)b2) + bf2f((ushort_t)(b2>>16));
  }
  __syncthreads();
  const int i = threadIdx.x & 63;
  const int rq = threadIdx.x >> 6;
  const float* wr = p.Wlin + (size_t)i*512;
  float sum[4] = {0.f,0.f,0.f,0.f};
  for (int k = 0; k < 512; k += 4){
    f32x4 wv = *(const f32x4*)(wr + k);
    #pragma unroll
    for (int q2=0;q2<4;++q2){
      const float* hfp = &lf[(rq*4+q2)*512 + k];
      sum[q2] += hfp[0]*wv[0] + hfp[1]*wv[1] + hfp[2]*wv[2] + hfp[3]*wv[3];
    }
  }
  #pragma unroll
  for (int q2=0;q2<4;++q2){
    const int row = r0 + rq*4 + q2;
    float v = sum[q2] + p.blin[i];
    p.out[(size_t)row*(NSTEPS*IIN) + d*IIN + i] = v;
    ushort_t oh, ol; split2(v, oh, ol);
    astore32(&p.outp[row*64 + i], (uint32_t)oh | ((uint32_t)ol<<16));
  }
  __syncthreads();
}

// ---- persistent kernel: XCD-ticket tile assignment + flag grid barrier ----
__global__ __launch_bounds__(256, 2)
void lstm_persist(KP p)
{
  __shared__ ushort_t lds[32768];   // 64 KB
  __shared__ int s_lt;
  if (threadIdx.x == 0){
    const int xcd = get_xcd();
    int lt = 0;
    for (int a = 0; a < 8; ++a){
      const int xx = (xcd + a) & 7;
      uint32_t idx = __hip_atomic_fetch_add(&p.assign[xx], 1u, __ATOMIC_RELAXED,
                                            __HIP_MEMORY_SCOPE_AGENT);
      if (idx < 64u){ lt = xx*64 + (int)idx; break; }
    }
    s_lt = lt;
  }
  __syncthreads();
  const int lt = s_lt;
  const int n = lt >> 6;
  const int li = lt & 63;
  const int role = li >> 5;
  const int m = li & 31;

  float c4[4] = {0.f,0.f,0.f,0.f};
  uint32_t* h0[2] = { p.h0a, p.h0b };
  uint32_t* h1[2] = { p.h1a, p.h1b };

  int slot = 0;
  auto gbar = [&](){
    __syncthreads();
    if (threadIdx.x == 0){
      uint32_t old = __hip_atomic_fetch_add(&p.bar[slot], 1u, __ATOMIC_RELAXED,
                                            __HIP_MEMORY_SCOPE_AGENT);
      if (old == (uint32_t)(NBLOCKS-1)){
        __hip_atomic_store(&p.rel[slot], 1u, __ATOMIC_RELAXED, __HIP_MEMORY_SCOPE_AGENT);
      } else {
        while (!__hip_atomic_load(&p.rel[slot], __ATOMIC_RELAXED, __HIP_MEMORY_SCOPE_AGENT))
          __builtin_amdgcn_s_sleep(1);
      }
    }
    __syncthreads();
    ++slot;
  };

  for (int s = 0; s <= TT; ++s){
    if (role == 0 && s < TT){
      role0_step(p, lds, m, n, p.x + (size_t)s*IIN, nullptr,
                 h0[(s+1)&1], h0[s&1], c4, nullptr);
    } else if (role == 1 && s >= 1){
      const int t = s-1;
      role1_step(p, lds, m, n, h0[t&1], h1[(t+1)&1], h1[t&1], c4, nullptr);
    }
    gbar();
  }
  int p0 = 1, p1 = 1;
  for (int d = 0; d < NSTEPS; ++d){
    if (role == 0){
      if (d == 0) role0_step(p, lds, m, n, p.x + (size_t)(TT-1)*IIN, nullptr,
                             h0[p0], h0[1-p0], c4, nullptr);
      else        role0_step(p, lds, m, n, nullptr, p.outp,
                             h0[p0], h0[1-p0], c4, nullptr);
    }
    gbar();
    if (role == 1) role1_step(p, lds, m, n, h0[1-p0], h1[p1], h1[1-p1], c4, nullptr);
    gbar();
    if (role == 0 && n == 0) lin_step(p, lds, m, d, h1[1-p1]);
    gbar();
    p0 ^= 1; p1 ^= 1;
  }
}

// ---- fallback per-step kernels (static tiles, c in global) ----
__global__ __launch_bounds__(256, 2)
void fb_enc(KP p, int s){
  __shared__ ushort_t lds[32768];
  uint32_t* h0[2] = { p.h0a, p.h0b };
  uint32_t* h1[2] = { p.h1a, p.h1b };
  const int bid = blockIdx.x;
  const int role = bid >> 8, tile = bid & 255, m = tile >> 3, n = tile & 7;
  if (role == 0 && s < TT)
    role0_step(p, lds, m, n, p.x + (size_t)s*IIN, nullptr,
               h0[(s+1)&1], h0[s&1], nullptr, p.c0m);
  else if (role == 1 && s >= 1){
    const int t = s-1;
    role1_step(p, lds, m, n, h0[t&1], h1[(t+1)&1], h1[t&1], nullptr, p.c1m);
  }
}
__global__ __launch_bounds__(256, 2)
void fb_dec0(KP p, int d, int p0){
  __shared__ ushort_t lds[32768];
  uint32_t* h0[2] = { p.h0a, p.h0b };
  const int m = blockIdx.x >> 3, n = blockIdx.x & 7;
  if (d == 0) role0_step(p, lds, m, n, p.x + (size_t)(TT-1)*IIN, nullptr,
                         h0[p0], h0[1-p0], nullptr, p.c0m);
  else        role0_step(p, lds, m, n, nullptr, p.outp,
                         h0[p0], h0[1-p0], nullptr, p.c0m);
}
__global__ __launch_bounds__(256, 2)
void fb_dec1(KP p, int p0, int p1){
  __shared__ ushort_t lds[32768];
  uint32_t* h0[2] = { p.h0a, p.h0b };
  uint32_t* h1[2] = { p.h1a, p.h1b };
  const int m = blockIdx.x >> 3, n = blockIdx.x & 7;
  role1_step(p, lds, m, n, h0[1-p0], h1[p1], h1[1-p1], nullptr, p.c1m);
}
__global__ __launch_bounds__(256)
void fb_lin(KP p, int d, int p1){
  __shared__ ushort_t lds[32768];
  uint32_t* h1[2] = { p.h1a, p.h1b };
  lin_step(p, lds, blockIdx.x, d, h1[1-p1]);
}

// ---- prep kernels ----
__global__ void bias_kernel(const float* a, const float* b, float* o){
  int i = blockIdx.x * 256 + threadIdx.x;
  if (i < 2048) o[i] = a[i] + b[i];
}

__global__ void prep_w(const float* __restrict__ Wih0, const float* __restrict__ Whh0,
                       const float* __restrict__ Wih1, const float* __restrict__ Whh1,
                       ushort_t* __restrict__ Wh, ushort_t* __restrict__ Wl)
{
  size_t i = (size_t)blockIdx.x*256 + threadIdx.x;
  if (i >= NTW) return;
  float val;
  if (i < N0W){
    int n   = (int)(i / W0TILE);
    int rem = (int)(i % W0TILE);
    int c   = rem / 8192;
    int rem2= rem & 8191;
    int cl  = rem2 >> 5;
    int q   = rem2 & 31;
    int k   = c*32 + q;
    int grow = ((cl>>4)&3)*512 + n*64 + ((cl>>6)&3)*16 + (cl&15);
    val = (k < 64) ? Wih0[(size_t)grow*64 + k] : Whh0[(size_t)grow*512 + (k-64)];
  } else {
    size_t e = i - N0W;
    int n   = (int)(e / W1TILE);
    int rem = (int)(e % W1TILE);
    int c   = rem / 8192;
    int rem2= rem & 8191;
    int cl  = rem2 >> 5;
    int q   = rem2 & 31;
    int k   = c*32 + q;
    int grow = ((cl>>4)&3)*512 + n*64 + ((cl>>6)&3)*16 + (cl&15);
    val = (k < 512) ? Wih1[(size_t)grow*512 + k] : Whh1[(size_t)grow*512 + (k-512)];
  }
  ushort_t h, lo2; split2(val, h, lo2);
  Wh[i] = h; Wl[i] = lo2;
}

extern "C" void kernel_launch(void* const* d_in, const int* in_sizes, int n_in,
                              void* d_out, int out_size, void* d_ws, size_t ws_size,
                              hipStream_t stream)
{
  const float* x     = (const float*)d_in[0];
  const float* W_ih0 = (const float*)d_in[1];
  const float* W_hh0 = (const float*)d_in[2];
  const float* b_ih0 = (const float*)d_in[3];
  const float* b_hh0 = (const float*)d_in[4];
  const float* W_ih1 = (const float*)d_in[5];
  const float* W_hh1 = (const float*)d_in[6];
  const float* b_ih1 = (const float*)d_in[7];
  const float* b_hh1 = (const float*)d_in[8];
  const float* W_lin = (const float*)d_in[9];
  const float* b_lin = (const float*)d_in[10];

  char* ws = (char*)d_ws;
  size_t off = 0;
  auto alloc = [&](size_t bytes){ size_t o = off; off += (bytes + 255) & ~(size_t)255; return o; };

  float* b0v = (float*)(ws + alloc(2048*4));
  float* b1v = (float*)(ws + alloc(2048*4));
  ushort_t* Wh = (ushort_t*)(ws + alloc(NTW*2));
  ushort_t* Wl = (ushort_t*)(ws + alloc(NTW*2));

  const size_t BH = (size_t)BSZ * HH;   // 262144
  // states (memset together): 4 packed h + 2 f32 c + outp + bar + rel + assign
  size_t statesBytes = 4*BH*4 + 2*BH*4 + (size_t)BSZ*IIN*4 + 512*4 + 512*4 + 16*4;
  char* states = ws + alloc(statesBytes);
  uint32_t* h0a = (uint32_t*)states;
  uint32_t* h0b = h0a + BH;
  uint32_t* h1a = h0a + 2*BH;
  uint32_t* h1b = h0a + 3*BH;
  float* c0m = (float*)(h0a + 4*BH);
  float* c1m = c0m + BH;
  uint32_t* outp = (uint32_t*)(c0m + 2*BH);
  uint32_t* bar  = outp + (size_t)BSZ*IIN;
  uint32_t* rel  = bar + 512;
  uint32_t* assign = rel + 512;

  bias_kernel<<<8, 256, 0, stream>>>(b_ih0, b_hh0, b0v);
  bias_kernel<<<8, 256, 0, stream>>>(b_ih1, b_hh1, b1v);
  prep_w<<<(int)((NTW+255)/256), 256, 0, stream>>>(W_ih0, W_hh0, W_ih1, W_hh1, Wh, Wl);
  hipMemsetAsync(states, 0, statesBytes, stream);

  KP kp;
  kp.x = x; kp.Wh = Wh; kp.Wl = Wl; kp.b0v = b0v; kp.b1v = b1v;
  kp.Wlin = W_lin; kp.blin = b_lin;
  kp.h0a = h0a; kp.h0b = h0b; kp.h1a = h1a; kp.h1b = h1b;
  kp.c0m = c0m; kp.c1m = c1m; kp.outp = outp;
  kp.out = (float*)d_out;
  kp.bar = bar; kp.rel = rel; kp.assign = assign;

  void* kargs[] = { &kp };
  hipError_t ce = hipLaunchCooperativeKernel((void*)lstm_persist,
                                             dim3(NBLOCKS), dim3(256), kargs, 0, stream);
  if (ce != hipSuccess){
    for (int s = 0; s <= TT; ++s)
      fb_enc<<<NBLOCKS, 256, 0, stream>>>(kp, s);
    int p0 = 1, p1 = 1;
    for (int d = 0; d < NSTEPS; ++d){
      fb_dec0<<<256, 256, 0, stream>>>(kp, d, p0);
      fb_dec1<<<256, 256, 0, stream>>>(kp, p0, p1);
      fb_lin<<<32, 256, 0, stream>>>(kp, d, p1);
      p0 ^= 1; p1 ^= 1;
    }
  }
}